// Round 1
// 145.807 us; speedup vs baseline: 1.0031x; 1.0031x over previous
//
#include <hip/hip_runtime.h>
#include <math.h>

#define BATCH 64
#define TOBS (1000 * 128)        // observations per batch
#define GROUPS (TOBS / 4)        // 32000 groups of 4 obs (12 floats, 48 B)
#define BPB 25                   // blocks per batch: 25*256*5 == 32000 exactly
#define BLOCK 256
#define ITERS 5

// ---- global -> LDS direct DMA (16 B per lane, wave-uniform LDS base) ----
__device__ __forceinline__ void gload_lds16(const float4* g, float4* l) {
    __builtin_amdgcn_global_load_lds(
        (const __attribute__((address_space(1))) void*)g,
        (__attribute__((address_space(3))) void*)l,
        16, 0, 0);
}

// Per-block partial sums -> ws[BATCH*BPB]; no memset / atomics needed.
//
// Load path (this round's change): per wave per tile, 3x global_load_lds_dwordx4,
// each 64 lanes x 16B CONTIGUOUS (1 KB/instr, ideal coalescing) vs the old
// stride-48 AoS reads (48 segments/instr). Double-buffered per-wave LDS slices,
// counted s_waitcnt vmcnt(3) keeps next tile's DMA in flight under compute.
// Source lane order is permuted within each 64-float4 chunk (same address set,
// so coalescing unchanged) so that the ds_read_b128 readback at word-stride 12
// lands on distinct bank-quads per lane (7l+5j mod 8) -> conflict-free.
__global__ __launch_bounds__(BLOCK) void score_kernel(const float* __restrict__ z,
                                                      const float* __restrict__ R,
                                                      float* __restrict__ ws,
                                                      float thresh2) {
    __shared__ float4 stage[8][192];   // [wave*2 + buf][slot], 24 KiB total

    const int b = blockIdx.x / BPB;
    const int chunk = blockIdx.x % BPB;
    const int w = threadIdx.x >> 6;
    const int l = threadIdx.x & 63;

    const float r = R[b];
    const float Bc = -0.5f / (r * r);
    // retire the R load so vmcnt below tracks only the stage DMAs
    asm volatile("s_waitcnt vmcnt(0)" ::: "memory");

    const float4* __restrict__ zb = (const float4*)(z + (size_t)b * (TOBS * 3));

    // swizzled source lane offset: slot 64k+l receives float4 64k + (61*l mod 64)
    const int lperm = (61 * l) & 63;
    // swizzled read slots: float4 f = 3l+j lives at slot (f & 192) + (21*(f&63) mod 64)
    const int f0 = 3 * l, f1 = 3 * l + 1, f2 = 3 * l + 2;
    const int rd0 = (f0 & 192) + ((21 * (f0 & 63)) & 63);
    const int rd1 = (f1 & 192) + ((21 * (f1 & 63)) & 63);
    const int rd2 = (f2 & 192) + ((21 * (f2 & 63)) & 63);

    const int base_grp = chunk * BLOCK + w * 64;   // wave's first group, iter 0

    // prologue: stage tile 0 into buffer 0
    {
        const float4* s = zb + (size_t)3 * base_grp + lperm;
        gload_lds16(s,       &stage[w * 2 + 0][0]);
        gload_lds16(s + 64,  &stage[w * 2 + 0][64]);
        gload_lds16(s + 128, &stage[w * 2 + 0][128]);
    }

    float acc = 0.0f;
    #pragma unroll
    for (int i = 0; i < ITERS; ++i) {
        const int p = i & 1;
        if (i + 1 < ITERS) {
            // prefetch next tile into the other buffer, then wait for current tile
            const float4* s = zb + (size_t)3 * (base_grp + (i + 1) * (BPB * BLOCK)) + lperm;
            gload_lds16(s,       &stage[w * 2 + (p ^ 1)][0]);
            gload_lds16(s + 64,  &stage[w * 2 + (p ^ 1)][64]);
            gload_lds16(s + 128, &stage[w * 2 + (p ^ 1)][128]);
            asm volatile("s_waitcnt vmcnt(3)" ::: "memory");
        } else {
            asm volatile("s_waitcnt vmcnt(0)" ::: "memory");
        }

        const float4 a0 = stage[w * 2 + p][rd0];
        const float4 a1 = stage[w * 2 + p][rd1];
        const float4 a2 = stage[w * 2 + p][rd2];
        const float z20 = a0.x * a0.x + a0.y * a0.y + a0.z * a0.z;
        const float z21 = a0.w * a0.w + a1.x * a1.x + a1.y * a1.y;
        const float z22 = a1.z * a1.z + a1.w * a1.w + a2.x * a2.x;
        const float z23 = a2.y * a2.y + a2.z * a2.z + a2.w * a2.w;
        acc += (z20 < thresh2) ? __expf(Bc * z20) : 0.0f;
        acc += (z21 < thresh2) ? __expf(Bc * z21) : 0.0f;
        acc += (z22 < thresh2) ? __expf(Bc * z22) : 0.0f;
        acc += (z23 < thresh2) ? __expf(Bc * z23) : 0.0f;
    }

    // wave-64 butterfly reduce
    #pragma unroll
    for (int off = 32; off > 0; off >>= 1)
        acc += __shfl_down(acc, off, 64);

    __shared__ float wave_sums[BLOCK / 64];
    const int wave = threadIdx.x >> 6;
    const int lane = threadIdx.x & 63;
    if (lane == 0) wave_sums[wave] = acc;
    __syncthreads();
    if (threadIdx.x == 0) {
        float t = 0.0f;
        #pragma unroll
        for (int ww = 0; ww < BLOCK / 64; ++ww) t += wave_sums[ww];
        ws[blockIdx.x] = t;    // per-block partial, no atomic
    }
}

__global__ void finalize_kernel(const float* __restrict__ ws,
                                const float* __restrict__ R,
                                const float* __restrict__ num_obs,
                                float* __restrict__ out,
                                float thresh2) {
    const int b = threadIdx.x;
    if (b >= BATCH) return;

    float rs = 0.0f;
    #pragma unroll
    for (int c = 0; c < BPB; ++c) rs += ws[b * BPB + c];

    const float r = R[b];
    const float A = 1.0f / (r * r);
    const float half = 0.5f * A * thresh2;
    const float mu_p = (1.0f - expf(-half)) / (2.0f * A);
    const float e2 = (1.0f - expf(-2.0f * half)) / (4.0f * A);
    const float var = e2 - mu_p * mu_p;
    const float nobs = num_obs[0];
    const float mu = nobs * mu_p;
    const float s2 = nobs * var;
    out[b] = rs;                       // raw_score
    out[BATCH + b] = mu;               // mu
    out[2 * BATCH + b] = s2;           // sigma2
    out[3 * BATCH + b] = rs - mu - s2; // objective
}

extern "C" void kernel_launch(void* const* d_in, const int* in_sizes, int n_in,
                              void* d_out, int out_size, void* d_ws, size_t ws_size,
                              hipStream_t stream) {
    const float* z = (const float*)d_in[0];        // (64,1000,128,3) f32
    const float* R = (const float*)d_in[1];        // (64,1) f32
    const float* num_obs = (const float*)d_in[2];  // scalar f32
    float* out = (float*)d_out;                    // 4*64 f32, concatenated
    float* ws = (float*)d_ws;                      // 1600 partials

    // THRESH2 exactly as numpy computes it (double math, then f32 cast)
    const double th = 2.0 * sin(M_PI / 180.0);     // = 2*sin(deg2rad(2)/2)
    const float thresh2 = (float)(th * th);

    score_kernel<<<dim3(BATCH * BPB), dim3(BLOCK), 0, stream>>>(z, R, ws, thresh2);
    finalize_kernel<<<dim3(1), dim3(64), 0, stream>>>(ws, R, num_obs, out, thresh2);
}